// Round 1
// baseline (317.666 us; speedup 1.0000x reference)
//
#include <hip/hip_runtime.h>
#include <math.h>

#define EPS 1e-20f
#define NPT 256            // FFT length / N
#define BB  512            // batch

// ---------------- kernel 0: normalize E rows ----------------
__global__ __launch_bounds__(256) void k_norm(const float* __restrict__ x,
                                              float2* __restrict__ Es) {
    int b = blockIdx.x;
    int j = threadIdx.x;
    float re = x[b * 512 + j];
    float im = x[b * 512 + 256 + j];
    float m = sqrtf(re * re + im * im);

    // block max reduce (4 waves)
    float v = m;
    #pragma unroll
    for (int off = 32; off; off >>= 1) v = fmaxf(v, __shfl_xor(v, off, 64));
    __shared__ float smax[4];
    if ((j & 63) == 0) smax[j >> 6] = v;
    __syncthreads();
    float mx = fmaxf(fmaxf(smax[0], smax[1]), fmaxf(smax[2], smax[3]));
    float inv = 1.0f / fmaxf(mx, EPS);
    Es[(b << 8) + j] = make_float2(re * inv, im * inv);
}

// ---------------- kernel 1: gate + 256-pt Stockham FFT + |.|^2 ----------------
// grid: 512 * 128 blocks, 256 threads; 2 rows per block (128 threads each)
__global__ __launch_bounds__(256) void k_fft(const float2* __restrict__ Es,
                                             float* __restrict__ out,
                                             unsigned int* __restrict__ bmax) {
    __shared__ float Er[256], Ei[256];
    __shared__ float Xr[2][2][256], Xi[2][2][256];  // [row-half][pingpong][elem]
    __shared__ float wmax[4];

    const int blk  = blockIdx.x;
    const int b    = blk >> 7;
    const int pair = blk & 127;
    const int tid  = threadIdx.x;
    const int half = tid >> 7;      // which row of the pair (wave-uniform)
    const int j    = tid & 127;     // butterfly index 0..127
    const int row  = pair * 2 + half;  // delay index i

    // stage E into LDS (normalized)
    float2 e = Es[(b << 8) + tid];
    Er[tid] = e.x; Ei[tid] = e.y;
    __syncthreads();

    // gate elems j and j+128 for this row, fused with FFT stage 0
    const int j2 = j + 128;
    const int s0i = (j  - row) & 255;
    const int s1i = (j2 - row) & 255;
    float ar = Er[j]  * Er[s0i] - Ei[j]  * Ei[s0i];
    float ai = Er[j]  * Ei[s0i] + Ei[j]  * Er[s0i];
    float br = Er[j2] * Er[s1i] - Ei[j2] * Ei[s1i];
    float bi = Er[j2] * Ei[s1i] + Ei[j2] * Er[s1i];

    const float W = -6.283185307179586f / 256.0f;
    float sw, cw;
    __sincosf((float)j * W, &sw, &cw);
    // stage 0: s=1, q=0 -> out0=2j, out1=2j+1
    Xr[half][0][2 * j]     = ar + br;
    Xi[half][0][2 * j]     = ai + bi;
    float dr = ar - br, di = ai - bi;
    Xr[half][0][2 * j + 1] = dr * cw - di * sw;
    Xi[half][0][2 * j + 1] = dr * sw + di * cw;

    int cur = 0;
    #pragma unroll
    for (int k = 1; k < 8; ++k) {
        __syncthreads();
        const int s = 1 << k;
        const int q = j & (s - 1);
        float xr = Xr[half][cur][j],       xi = Xi[half][cur][j];
        float yr = Xr[half][cur][j + 128], yi = Xi[half][cur][j + 128];
        const int tw = j & ~(s - 1);
        __sincosf((float)tw * W, &sw, &cw);
        const int o0 = 2 * j - q;
        const int nxt = cur ^ 1;
        Xr[half][nxt][o0]     = xr + yr;
        Xi[half][nxt][o0]     = xi + yi;
        dr = xr - yr; di = xi - yi;
        Xr[half][nxt][o0 + s] = dr * cw - di * sw;
        Xi[half][nxt][o0 + s] = dr * sw + di * cw;
        cur = nxt;
    }
    __syncthreads();

    // epilogue: |spec|^2 with fftshift(both axes) + reverse(last axis)
    const int iout = row ^ 128;                       // (row+128) % 256
    const size_t baseo = ((size_t)b << 16) + ((size_t)iout << 8);
    float m = 0.0f;
    #pragma unroll
    for (int kk = 0; kk < 2; ++kk) {
        const int k = j + kk * 128;
        float r = Xr[half][cur][k], im2 = Xi[half][cur][k];
        float I = r * r + im2 * im2;
        m = fmaxf(m, I);
        const int kout = (127 - k) & 255;
        out[baseo + kout] = I;
    }

    // per-batch max via block reduce + device atomicMax (float bits, I>=0)
    #pragma unroll
    for (int off = 32; off; off >>= 1) m = fmaxf(m, __shfl_xor(m, off, 64));
    if ((tid & 63) == 0) wmax[tid >> 6] = m;
    __syncthreads();
    if (tid == 0) {
        float mm = fmaxf(fmaxf(wmax[0], wmax[1]), fmaxf(wmax[2], wmax[3]));
        atomicMax(bmax + b, __float_as_uint(mm));
    }
}

// ---------------- kernel 2: in-place normalize ----------------
__global__ __launch_bounds__(256) void k_scale(float* __restrict__ out,
                                               const unsigned int* __restrict__ bmax) {
    size_t idx = (size_t)blockIdx.x * 256 + threadIdx.x;   // float4 index
    int b = (int)(idx >> 14);                              // 2^14 float4 per batch
    float mx = __uint_as_float(bmax[b]);
    float inv = 1.0f / fmaxf(mx, EPS);
    float4* p = (float4*)out;
    float4 v = p[idx];
    v.x *= inv; v.y *= inv; v.z *= inv; v.w *= inv;
    p[idx] = v;
}

extern "C" void kernel_launch(void* const* d_in, const int* in_sizes, int n_in,
                              void* d_out, int out_size, void* d_ws, size_t ws_size,
                              hipStream_t stream) {
    const float* x = (const float*)d_in[0];
    float* out = (float*)d_out;
    float2* Es = (float2*)d_ws;                               // 512*256*8 = 1 MiB
    unsigned int* bmax = (unsigned int*)((char*)d_ws + (size_t)BB * NPT * sizeof(float2));

    hipMemsetAsync(bmax, 0, BB * sizeof(unsigned int), stream);
    k_norm<<<BB, 256, 0, stream>>>(x, Es);
    k_fft<<<BB * 128, 256, 0, stream>>>(Es, out, bmax);
    k_scale<<<(BB * NPT * NPT) / (4 * 256), 256, 0, stream>>>(out, bmax);
}

// Round 2
// 263.774 us; speedup vs baseline: 1.2043x; 1.2043x over previous
//
#include <hip/hip_runtime.h>
#include <math.h>

#define EPS 1e-20f
#define NPT 256
#define BB  512

__device__ __forceinline__ int PX(int e) { return e + (e >> 3); }

__device__ __forceinline__ float4 f4add(float4 a, float4 b) {
    return make_float4(a.x + b.x, a.y + b.y, a.z + b.z, a.w + b.w);
}
__device__ __forceinline__ float4 f4sub(float4 a, float4 b) {
    return make_float4(a.x - b.x, a.y - b.y, a.z - b.z, a.w - b.w);
}
// multiply both packed complex by -i:  -i*(x+iy) = y - ix
__device__ __forceinline__ float4 mulmi(float4 v) {
    return make_float4(v.y, -v.x, v.w, -v.z);
}
// multiply both packed complex by (c + i s)
__device__ __forceinline__ float4 cmul4(float4 v, float c, float s) {
    return make_float4(v.x * c - v.y * s, v.x * s + v.y * c,
                       v.z * c - v.w * s, v.z * s + v.w * c);
}

// radix-4 DIF butterfly on a[0..3]; output a[t] goes to position n' + t*M/4.
// th = -2*pi*n'/M.  tw=false for the last stage (all twiddles = 1).
__device__ __forceinline__ void radix4(float4* a, float th, bool tw) {
    float4 s0  = f4add(a[0], a[2]);
    float4 s1  = f4add(a[1], a[3]);
    float4 d0  = f4sub(a[0], a[2]);
    float4 d1m = mulmi(f4sub(a[1], a[3]));
    float4 b0 = f4add(s0, s1);
    float4 b1 = f4add(d0, d1m);
    float4 b2 = f4sub(s0, s1);
    float4 b3 = f4sub(d0, d1m);
    if (tw) {
        float s, c;
        __sincosf(th, &s, &c);
        float c2 = c * c - s * s, s2 = 2.f * c * s;
        float c3 = c * c2 - s * s2, s3 = c * s2 + s * c2;
        b1 = cmul4(b1, c, s);
        b2 = cmul4(b2, c2, s2);
        b3 = cmul4(b3, c3, s3);
    }
    a[0] = b0; a[1] = b1; a[2] = b2; a[3] = b3;
}

// ---------------- kernel 0: normalize E rows ----------------
__global__ __launch_bounds__(256) void k_norm(const float* __restrict__ x,
                                              float2* __restrict__ Es) {
    int b = blockIdx.x;
    int j = threadIdx.x;
    float re = x[b * 512 + j];
    float im = x[b * 512 + 256 + j];
    float m = sqrtf(re * re + im * im);
    float v = m;
    #pragma unroll
    for (int off = 32; off; off >>= 1) v = fmaxf(v, __shfl_xor(v, off, 64));
    __shared__ float smax[4];
    if ((j & 63) == 0) smax[j >> 6] = v;
    __syncthreads();
    float mx = fmaxf(fmaxf(smax[0], smax[1]), fmaxf(smax[2], smax[3]));
    float inv = 1.0f / fmaxf(mx, EPS);
    Es[(b << 8) + j] = make_float2(re * inv, im * inv);
}

// ---------------- kernel 1: gate + radix-4 in-place FFT + |.|^2 ----------------
// grid: 512*32 blocks, 256 threads = 4 waves; each wave: 2 rows packed in float4
__global__ __launch_bounds__(256) void k_fft(const float2* __restrict__ Es,
                                             float* __restrict__ out,
                                             unsigned int* __restrict__ bmax) {
    __shared__ float2 El[256];
    __shared__ float4 X[4][288];   // 256 + 256/8 pad, per wave

    const int tid = threadIdx.x;
    const int w = tid >> 6;
    const int l = tid & 63;
    const int b = blockIdx.x >> 5;
    const int i0 = (blockIdx.x & 31) * 8 + w * 2;   // row pair (i0, i0+1)
    const int i1 = i0 + 1;

    El[tid] = Es[(b << 8) + tid];
    __syncthreads();

    const float TH = -6.283185307179586f;
    float4 a[4];

    // ---- gate (both rows) + stage 0 (M=256, n'=l), fused in registers ----
    #pragma unroll
    for (int m = 0; m < 4; ++m) {
        int j = l + 64 * m;
        float2 e  = El[j];
        float2 s0 = El[(j - i0) & 255];
        float2 s1 = El[(j - i1) & 255];
        a[m] = make_float4(e.x * s0.x - e.y * s0.y, e.x * s0.y + e.y * s0.x,
                           e.x * s1.x - e.y * s1.y, e.x * s1.y + e.y * s1.x);
    }
    radix4(a, TH * (float)l / 256.0f, true);
    #pragma unroll
    for (int t = 0; t < 4; ++t) X[w][PX(l + 64 * t)] = a[t];

    // ---- stage 1 (M=64): segment q=l>>4, n'=l&15, elems 64q+n'+16m ----
    {
        int base = 64 * (l >> 4) + (l & 15);
        #pragma unroll
        for (int m = 0; m < 4; ++m) a[m] = X[w][PX(base + 16 * m)];
        radix4(a, TH * (float)(l & 15) / 64.0f, true);
        #pragma unroll
        for (int t = 0; t < 4; ++t) X[w][PX(base + 16 * t)] = a[t];
    }
    // ---- stage 2 (M=16): segment s=l>>2, n'=l&3, elems 16s+n'+4m ----
    {
        int base = 16 * (l >> 2) + (l & 3);
        #pragma unroll
        for (int m = 0; m < 4; ++m) a[m] = X[w][PX(base + 4 * m)];
        radix4(a, TH * (float)(l & 3) / 16.0f, true);
        #pragma unroll
        for (int t = 0; t < 4; ++t) X[w][PX(base + 4 * t)] = a[t];
    }
    // ---- stage 3 (M=4): elems 4l+m, no twiddle; fuse epilogue ----
    #pragma unroll
    for (int m = 0; m < 4; ++m) a[m] = X[w][PX(4 * l + m)];
    radix4(a, 0.0f, false);

    // in-place position p = 4l+t  ->  freq k = digit-reverse_4(p) = 64t + revd
    const int revd = 16 * (l & 3) + 4 * ((l >> 2) & 3) + (l >> 4);
    const size_t base0 = ((size_t)b << 16) + ((size_t)(i0 ^ 128) << 8);
    const size_t base1 = ((size_t)b << 16) + ((size_t)(i1 ^ 128) << 8);
    float mx = 0.0f;
    #pragma unroll
    for (int t = 0; t < 4; ++t) {
        float I0 = a[t].x * a[t].x + a[t].y * a[t].y;
        float I1 = a[t].z * a[t].z + a[t].w * a[t].w;
        int kout = (127 - (64 * t + revd)) & 255;
        out[base0 + kout] = I0;
        out[base1 + kout] = I1;
        mx = fmaxf(mx, fmaxf(I0, I1));
    }
    #pragma unroll
    for (int off = 32; off; off >>= 1) mx = fmaxf(mx, __shfl_xor(mx, off, 64));
    if (l == 0) atomicMax(bmax + b, __float_as_uint(mx));
}

// ---------------- kernel 2: in-place normalize ----------------
__global__ __launch_bounds__(256) void k_scale(float* __restrict__ out,
                                               const unsigned int* __restrict__ bmax) {
    size_t idx = (size_t)blockIdx.x * 256 + threadIdx.x;   // float4 index
    int b = (int)(idx >> 14);                              // 2^14 float4 per batch
    float mx = __uint_as_float(bmax[b]);
    float inv = 1.0f / fmaxf(mx, EPS);
    float4* p = (float4*)out;
    float4 v = p[idx];
    v.x *= inv; v.y *= inv; v.z *= inv; v.w *= inv;
    p[idx] = v;
}

extern "C" void kernel_launch(void* const* d_in, const int* in_sizes, int n_in,
                              void* d_out, int out_size, void* d_ws, size_t ws_size,
                              hipStream_t stream) {
    const float* x = (const float*)d_in[0];
    float* out = (float*)d_out;
    float2* Es = (float2*)d_ws;
    unsigned int* bmax = (unsigned int*)((char*)d_ws + (size_t)BB * NPT * sizeof(float2));

    hipMemsetAsync(bmax, 0, BB * sizeof(unsigned int), stream);
    k_norm<<<BB, 256, 0, stream>>>(x, Es);
    k_fft<<<BB * 32, 256, 0, stream>>>(Es, out, bmax);
    k_scale<<<(BB * NPT * NPT) / (4 * 256), 256, 0, stream>>>(out, bmax);
}

// Round 3
// 221.871 us; speedup vs baseline: 1.4318x; 1.1889x over previous
//
#include <hip/hip_runtime.h>
#include <hip/hip_fp16.h>
#include <math.h>

#define EPS 1e-20f
#define NPT 256
#define BB  512

// ---- complex float2 helpers ----
__device__ __forceinline__ float2 cadd(float2 a, float2 b){ return make_float2(a.x+b.x, a.y+b.y); }
__device__ __forceinline__ float2 csub(float2 a, float2 b){ return make_float2(a.x-b.x, a.y-b.y); }
__device__ __forceinline__ float2 cmul(float2 a, float2 b){ return make_float2(a.x*b.x - a.y*b.y, a.x*b.y + a.y*b.x); }
__device__ __forceinline__ float2 cmulc(float2 a, float c, float s){ return make_float2(a.x*c - a.y*s, a.x*s + a.y*c); }
__device__ __forceinline__ float2 cmulmi(float2 a){ return make_float2(a.y, -a.x); }   // * (-i)

// radix-4 DIF butterfly in place (natural order for N=4: out t = X[t])
__device__ __forceinline__ void bfly4(float2& c0, float2& c1, float2& c2, float2& c3) {
    float2 s0 = cadd(c0, c2), s1 = cadd(c1, c3);
    float2 d0 = csub(c0, c2), d1 = cmulmi(csub(c1, c3));
    c0 = cadd(s0, s1); c1 = cadd(d0, d1); c2 = csub(s0, s1); c3 = csub(d0, d1);
}

// W16^j = (cos(pi j/8), -sin(pi j/8))
#define C16_1 0.9238795325112867f
#define S16_1 (-0.3826834323650898f)
#define C16_2 0.7071067811865476f
#define S16_2 (-0.7071067811865476f)
#define C16_3 0.3826834323650898f
#define S16_3 (-0.9238795325112867f)
#define C16_6 (-0.7071067811865476f)
#define S16_6 (-0.7071067811865476f)
#define C16_9 (-0.9238795325112867f)
#define S16_9 0.3826834323650898f

// in-place 16-pt DIF DFT; position p ends up holding frequency r4(p)=4(p&3)+(p>>2)
__device__ __forceinline__ void dft16(float2* x) {
    // stage A (M=16): butterflies over {n', n'+4, n'+8, n'+12}, twiddle W16^{n' t}
    bfly4(x[0], x[4], x[8], x[12]);               // n'=0
    bfly4(x[1], x[5], x[9], x[13]);               // n'=1
    x[5]  = cmulc(x[5],  C16_1, S16_1);
    x[9]  = cmulc(x[9],  C16_2, S16_2);
    x[13] = cmulc(x[13], C16_3, S16_3);
    bfly4(x[2], x[6], x[10], x[14]);              // n'=2
    x[6]  = cmulc(x[6],  C16_2, S16_2);
    x[10] = cmulmi(x[10]);                        // W16^4 = -i
    x[14] = cmulc(x[14], C16_6, S16_6);
    bfly4(x[3], x[7], x[11], x[15]);              // n'=3
    x[7]  = cmulc(x[7],  C16_3, S16_3);
    x[11] = cmulc(x[11], C16_6, S16_6);
    x[15] = cmulc(x[15], C16_9, S16_9);
    // stage B (M=4): no twiddles
    bfly4(x[0],  x[1],  x[2],  x[3]);
    bfly4(x[4],  x[5],  x[6],  x[7]);
    bfly4(x[8],  x[9],  x[10], x[11]);
    bfly4(x[12], x[13], x[14], x[15]);
}

// ---------------- kernel 0: normalize E rows ----------------
__global__ __launch_bounds__(256) void k_norm(const float* __restrict__ x,
                                              float2* __restrict__ Es) {
    int b = blockIdx.x;
    int j = threadIdx.x;
    float re = x[b * 512 + j];
    float im = x[b * 512 + 256 + j];
    float v = sqrtf(re * re + im * im);
    #pragma unroll
    for (int off = 32; off; off >>= 1) v = fmaxf(v, __shfl_xor(v, off, 64));
    __shared__ float smax[4];
    if ((j & 63) == 0) smax[j >> 6] = v;
    __syncthreads();
    float mx = fmaxf(fmaxf(smax[0], smax[1]), fmaxf(smax[2], smax[3]));
    float inv = 1.0f / fmaxf(mx, EPS);
    Es[(b << 8) + j] = make_float2(re * inv, im * inv);
}

// ---------------- kernel 1: gate + radix-16^2 FFT + |.|^2 ----------------
// grid: 512*16 blocks, 256 threads; 16 lanes per row -> 16 rows per block.
// lane l holds column n2=l; 16 regs hold n1=0..15 (j = 16*n1 + l).
__global__ __launch_bounds__(256) void k_fft(const float2* __restrict__ Es,
                                             float* __restrict__ out,
                                             unsigned int* __restrict__ bmax) {
    __shared__ float2 El[256];
    __shared__ float2 Wt[256];           // W256^t
    __shared__ __half2 T[16][272];       // per-group 16x16 transpose, stride 17

    const int tid = threadIdx.x;
    const int G   = tid >> 4;            // group 0..15 (one row each)
    const int l   = tid & 15;            // n2 / column
    const int b   = blockIdx.x >> 4;
    const int i   = (blockIdx.x & 15) * 16 + G;   // delay row

    El[tid] = Es[(b << 8) + tid];
    {
        float s, c;
        __sincosf(-6.283185307179586f * (float)tid / 256.0f, &s, &c);
        Wt[tid] = make_float2(c, s);
    }
    __syncthreads();

    // digit-reversal r4(p) = 4*(p&3) + (p>>2) as a constexpr table
    const int R4[16] = {0,4,8,12, 1,5,9,13, 2,6,10,14, 3,7,11,15};

    float2 x[16];
    // ---- gate: x[n1] = E[16n1+l] * E[(16n1+l-i)&255] ----
    #pragma unroll
    for (int n1 = 0; n1 < 16; ++n1) {
        int j = 16 * n1 + l;
        x[n1] = cmul(El[j], El[(j - i) & 255]);
    }

    // ---- inner DFT over n1 ----
    dft16(x);    // x[p1] = Y[k1=r4(p1)][l]

    // ---- twiddle W256^{k1 * n2} and pack to half2 transpose buffer ----
    #pragma unroll
    for (int p1 = 0; p1 < 16; ++p1) {
        float2 y = x[p1];
        if (p1 != 0) {                       // r4(0)=0 -> W=1
            float2 w = Wt[R4[p1] * l];       // idx <= 225
            y = cmul(y, w);
        }
        T[G][p1 * 17 + l] = __floats2half2_rn(y.x, y.y);
    }

    // ---- transpose read: lane l now owns k1 = r4(l), regs over n2=j ----
    #pragma unroll
    for (int j = 0; j < 16; ++j) {
        __half2 h = T[G][l * 17 + j];
        x[j] = make_float2(__low2float(h), __high2float(h));
    }

    // ---- outer DFT over n2 ----
    dft16(x);    // x[p2] = X[k1 + 16*r4(p2)]

    // ---- epilogue: I = |X|^2, fftshift both axes + reverse last axis ----
    const int k1 = 4 * (l & 3) + (l >> 2);       // r4(l)
    const int v  = 127 - k1;
    const size_t base = ((size_t)b << 16) + ((size_t)(i ^ 128) << 8);
    float mx = 0.0f;
    #pragma unroll
    for (int p2 = 0; p2 < 16; ++p2) {
        float I = x[p2].x * x[p2].x + x[p2].y * x[p2].y;
        int kout = (v - 16 * R4[p2]) & 255;
        out[base + kout] = I;
        mx = fmaxf(mx, I);
    }

    // per-batch max: wave reduce + one atomic per wave
    #pragma unroll
    for (int off = 32; off; off >>= 1) mx = fmaxf(mx, __shfl_xor(mx, off, 64));
    if ((tid & 63) == 0) atomicMax(bmax + b, __float_as_uint(mx));
}

// ---------------- kernel 2: in-place normalize ----------------
__global__ __launch_bounds__(256) void k_scale(float* __restrict__ out,
                                               const unsigned int* __restrict__ bmax) {
    size_t idx = (size_t)blockIdx.x * 256 + threadIdx.x;   // float4 index
    int b = (int)(idx >> 14);                              // 2^14 float4 per batch
    float mx = __uint_as_float(bmax[b]);
    float inv = 1.0f / fmaxf(mx, EPS);
    float4* p = (float4*)out;
    float4 vv = p[idx];
    vv.x *= inv; vv.y *= inv; vv.z *= inv; vv.w *= inv;
    p[idx] = vv;
}

extern "C" void kernel_launch(void* const* d_in, const int* in_sizes, int n_in,
                              void* d_out, int out_size, void* d_ws, size_t ws_size,
                              hipStream_t stream) {
    const float* x = (const float*)d_in[0];
    float* out = (float*)d_out;
    float2* Es = (float2*)d_ws;
    unsigned int* bmax = (unsigned int*)((char*)d_ws + (size_t)BB * NPT * sizeof(float2));

    hipMemsetAsync(bmax, 0, BB * sizeof(unsigned int), stream);
    k_norm<<<BB, 256, 0, stream>>>(x, Es);
    k_fft<<<BB * 16, 256, 0, stream>>>(Es, out, bmax);
    k_scale<<<(BB * NPT * NPT) / (4 * 256), 256, 0, stream>>>(out, bmax);
}

// Round 4
// 213.796 us; speedup vs baseline: 1.4858x; 1.0378x over previous
//
#include <hip/hip_runtime.h>
#include <hip/hip_fp16.h>
#include <math.h>

#define EPS 1e-20f
#define NPT 256
#define BB  512

// ---- complex float2 helpers ----
__device__ __forceinline__ float2 cadd(float2 a, float2 b){ return make_float2(a.x+b.x, a.y+b.y); }
__device__ __forceinline__ float2 csub(float2 a, float2 b){ return make_float2(a.x-b.x, a.y-b.y); }
__device__ __forceinline__ float2 cmul(float2 a, float2 b){ return make_float2(a.x*b.x - a.y*b.y, a.x*b.y + a.y*b.x); }
__device__ __forceinline__ float2 cmulc(float2 a, float c, float s){ return make_float2(a.x*c - a.y*s, a.x*s + a.y*c); }
__device__ __forceinline__ float2 cmulmi(float2 a){ return make_float2(a.y, -a.x); }   // * (-i)

__device__ __forceinline__ void bfly4(float2& c0, float2& c1, float2& c2, float2& c3) {
    float2 s0 = cadd(c0, c2), s1 = cadd(c1, c3);
    float2 d0 = csub(c0, c2), d1 = cmulmi(csub(c1, c3));
    c0 = cadd(s0, s1); c1 = cadd(d0, d1); c2 = csub(s0, s1); c3 = csub(d0, d1);
}

#define C16_1 0.9238795325112867f
#define S16_1 (-0.3826834323650898f)
#define C16_2 0.7071067811865476f
#define S16_2 (-0.7071067811865476f)
#define C16_3 0.3826834323650898f
#define S16_3 (-0.9238795325112867f)
#define C16_6 (-0.7071067811865476f)
#define S16_6 (-0.7071067811865476f)
#define C16_9 (-0.9238795325112867f)
#define S16_9 0.3826834323650898f

// in-place 16-pt DIF DFT; position p ends up holding frequency r4(p)=4(p&3)+(p>>2)
__device__ __forceinline__ void dft16(float2* x) {
    bfly4(x[0], x[4], x[8], x[12]);
    bfly4(x[1], x[5], x[9], x[13]);
    x[5]  = cmulc(x[5],  C16_1, S16_1);
    x[9]  = cmulc(x[9],  C16_2, S16_2);
    x[13] = cmulc(x[13], C16_3, S16_3);
    bfly4(x[2], x[6], x[10], x[14]);
    x[6]  = cmulc(x[6],  C16_2, S16_2);
    x[10] = cmulmi(x[10]);
    x[14] = cmulc(x[14], C16_6, S16_6);
    bfly4(x[3], x[7], x[11], x[15]);
    x[7]  = cmulc(x[7],  C16_3, S16_3);
    x[11] = cmulc(x[11], C16_6, S16_6);
    x[15] = cmulc(x[15], C16_9, S16_9);
    bfly4(x[0],  x[1],  x[2],  x[3]);
    bfly4(x[4],  x[5],  x[6],  x[7]);
    bfly4(x[8],  x[9],  x[10], x[11]);
    bfly4(x[12], x[13], x[14], x[15]);
}

#define R4C(p) ((((p) & 3) << 2) | ((p) >> 2))

// ---------------- kernel 1: gate + radix-16^2 FFT + |.|^2 ----------------
// grid: 512*16 blocks, 256 threads; 16 lanes per row -> 16 rows per block.
// HALFWS=1: store I*2^-12 as __half into ws; HALFWS=0: store fp32 I into out.
template<int HALFWS>
__global__ __launch_bounds__(256) void k_fft(const float* __restrict__ xin,
                                             void* __restrict__ dst,
                                             unsigned int* __restrict__ bmax) {
    __shared__ float2 El[256];
    __shared__ __half2 T[16 * 328];   // per group: 16 rows x stride 20 (+8 group stagger)

    const int tid = threadIdx.x;
    const int G   = tid >> 4;
    const int l   = tid & 15;
    const int b   = blockIdx.x >> 4;
    const int i   = (blockIdx.x & 15) * 16 + G;

    // stage raw E (normalization cancels in I/max(I))
    El[tid] = make_float2(xin[b * 512 + tid], xin[b * 512 + 256 + tid]);
    __syncthreads();

    float2 x[16];
    // ---- gate: x[n1] = E[16n1+l] * E[(16n1+l-i)&255] ----
    #pragma unroll
    for (int n1 = 0; n1 < 16; ++n1) {
        int j = 16 * n1 + l;
        x[n1] = cmul(El[j], El[(j - i) & 255]);
    }

    // ---- inner DFT over n1: x[p1] = Y[k1=r4(p1)][n2=l] ----
    dft16(x);

    // ---- transpose through LDS (half2), b128 writes ----
    {
        float4* wp = (float4*)&T[G * 328 + l * 20];
        #pragma unroll
        for (int q = 0; q < 4; ++q) {
            float4 pk;
            __half2* hp = (__half2*)&pk;
            hp[0] = __floats2half2_rn(x[4 * q + 0].x, x[4 * q + 0].y);
            hp[1] = __floats2half2_rn(x[4 * q + 1].x, x[4 * q + 1].y);
            hp[2] = __floats2half2_rn(x[4 * q + 2].x, x[4 * q + 2].y);
            hp[3] = __floats2half2_rn(x[4 * q + 3].x, x[4 * q + 3].y);
            wp[q] = pk;
        }
    }
    // same wave -> lockstep -> no barrier needed
    #pragma unroll
    for (int j = 0; j < 16; ++j) {
        x[j] = __half22float2(T[G * 328 + j * 20 + l]);
    }

    // ---- twiddle W256^{k1*n2} via register powers; k1 = r4(l) ----
    const int k1 = R4C(l);
    float sn, cs;
    __sincosf(-0.024543692606170259f * (float)k1, &sn, &cs);   // -2pi/256 * k1
    float2 w1 = make_float2(cs, sn);
    float2 w2 = cmul(w1, w1), w3 = cmul(w2, w1);
    float2 w4 = cmul(w2, w2), w8 = cmul(w4, w4), w12 = cmul(w8, w4);
    x[1]  = cmul(x[1],  w1);
    x[2]  = cmul(x[2],  w2);
    x[3]  = cmul(x[3],  w3);
    x[4]  = cmul(x[4],  w4);
    x[5]  = cmul(cmul(x[5],  w1), w4);
    x[6]  = cmul(cmul(x[6],  w2), w4);
    x[7]  = cmul(cmul(x[7],  w3), w4);
    x[8]  = cmul(x[8],  w8);
    x[9]  = cmul(cmul(x[9],  w1), w8);
    x[10] = cmul(cmul(x[10], w2), w8);
    x[11] = cmul(cmul(x[11], w3), w8);
    x[12] = cmul(x[12], w12);
    x[13] = cmul(cmul(x[13], w1), w12);
    x[14] = cmul(cmul(x[14], w2), w12);
    x[15] = cmul(cmul(x[15], w3), w12);

    // ---- outer DFT over n2: x[p2] = X[k1 + 16*r4(p2)] ----
    dft16(x);

    // ---- epilogue: I = |X|^2, fftshift both axes + reverse last axis ----
    const int v = 127 - k1;
    const size_t rbase = ((size_t)b << 16) + ((size_t)(i ^ 128) << 8);
    float mx = 0.0f;
    #pragma unroll
    for (int p2 = 0; p2 < 16; ++p2) {
        float I = x[p2].x * x[p2].x + x[p2].y * x[p2].y;
        int kout = (v - 16 * R4C(p2)) & 255;
        if (HALFWS)
            ((__half*)dst)[rbase + kout] = __float2half_rn(I * 0.000244140625f);  // I * 2^-12
        else
            ((float*)dst)[rbase + kout] = I;
        mx = fmaxf(mx, I);
    }

    #pragma unroll
    for (int off = 32; off; off >>= 1) mx = fmaxf(mx, __shfl_xor(mx, off, 64));
    if ((tid & 63) == 0) atomicMax(bmax + b, __float_as_uint(mx));
}

// ---------------- kernel 2a: half ws -> normalized fp32 out ----------------
__global__ __launch_bounds__(256) void k_scale_h(const float4* __restrict__ ws,
                                                 float4* __restrict__ out,
                                                 const unsigned int* __restrict__ bmax) {
    size_t t = (size_t)blockIdx.x * 256 + threadIdx.x;   // 8 halves / thread
    int b = (int)(t >> 13);                              // 8192 threads per batch
    float inv = 4096.0f / fmaxf(__uint_as_float(bmax[b]), EPS);
    float4 v = ws[t];
    const __half2* h = (const __half2*)&v;
    float2 f0 = __half22float2(h[0]);
    float2 f1 = __half22float2(h[1]);
    float2 f2 = __half22float2(h[2]);
    float2 f3 = __half22float2(h[3]);
    out[2 * t]     = make_float4(f0.x * inv, f0.y * inv, f1.x * inv, f1.y * inv);
    out[2 * t + 1] = make_float4(f2.x * inv, f2.y * inv, f3.x * inv, f3.y * inv);
}

// ---------------- kernel 2b: fallback in-place fp32 normalize ----------------
__global__ __launch_bounds__(256) void k_scale_f(float* __restrict__ out,
                                                 const unsigned int* __restrict__ bmax) {
    size_t idx = (size_t)blockIdx.x * 256 + threadIdx.x;   // float4 index
    int b = (int)(idx >> 14);
    float inv = 1.0f / fmaxf(__uint_as_float(bmax[b]), EPS);
    float4* p = (float4*)out;
    float4 v = p[idx];
    v.x *= inv; v.y *= inv; v.z *= inv; v.w *= inv;
    p[idx] = v;
}

extern "C" void kernel_launch(void* const* d_in, const int* in_sizes, int n_in,
                              void* d_out, int out_size, void* d_ws, size_t ws_size,
                              hipStream_t stream) {
    const float* x = (const float*)d_in[0];
    float* out = (float*)d_out;

    const size_t halfBytes = (size_t)BB * NPT * NPT * sizeof(__half);   // 64 MiB
    const bool useHalf = ws_size >= halfBytes + 4096;

    unsigned int* bmax = (unsigned int*)((char*)d_ws + (useHalf ? halfBytes : 0));
    hipMemsetAsync(bmax, 0, BB * sizeof(unsigned int), stream);

    if (useHalf) {
        k_fft<1><<<BB * 16, 256, 0, stream>>>(x, d_ws, bmax);
        k_scale_h<<<BB * NPT * NPT / (8 * 256), 256, 0, stream>>>(
            (const float4*)d_ws, (float4*)out, bmax);
    } else {
        k_fft<0><<<BB * 16, 256, 0, stream>>>(x, out, bmax);
        k_scale_f<<<BB * NPT * NPT / (4 * 256), 256, 0, stream>>>(out, bmax);
    }
}